// Round 13
// baseline (148.248 us; speedup 1.0000x reference)
//
#include <hip/hip_runtime.h>
#include <math.h>

#define EPSC 1e-6f
#define THETAC 1e-3f
#define C1C 1e-4f
#define C2C 9e-4f
#define DEN_EPS 1e-12f

constexpr int Bn = 4, Cn = 16, Hn = 512, Wn = 512;
constexpr int HW = Hn * Wn;          // 262144 = 2^18
constexpr int NP = Bn * HW;          // 1048576
constexpr int TS = 32, RAD = 5, K = 11;
constexpr int HALO = TS + 2 * RAD;   // 42
constexpr int HP = 33;               // horizontal-sum pitch (linear, conflict-free)
constexpr int HSZ = HALO * HP;       // 1386
constexpr int tiles_x = Wn / TS;     // 16
constexpr int NT = tiles_x * (Hn / TS); // 256

// 48-wide aligned window, pitch 49 (k_ssim only)
constexpr int PW = 49;
constexpr int SSZ = HALO * PW;       // 2058

__device__ __forceinline__ int refl(int i, int n) {
    if (i < 0) i = -i;
    if (i >= n) i = 2 * n - 2 - i;
    return i;
}

__device__ __forceinline__ int swz_tile(int x) { return (x & 7) * (NT / 8) + (x >> 3); }

__device__ __forceinline__ unsigned int bf16pack(float a, float b) {
    unsigned int ua = __float_as_uint(a), ub = __float_as_uint(b);
    ua += 0x7FFFu + ((ua >> 16) & 1u);
    ub += 0x7FFFu + ((ub >> 16) & 1u);
    return (ua >> 16) | (ub & 0xFFFF0000u);
}
__device__ __forceinline__ float bflo(unsigned int v) { return __uint_as_float(v << 16); }
__device__ __forceinline__ float bfhi(unsigned int v) { return __uint_as_float(v & 0xFFFF0000u); }

// vbox4 over float2 h
__device__ __forceinline__ void vbox4_2(const float2* h2, int x, int r0, float2 m[4]) {
    const float inv = 1.f / 121.f;
    const float2* hb = h2 + r0 * HP + x;
    float2 s = hb[0];
#pragma unroll
    for (int dy = 1; dy < K; ++dy) {
        float2 v = hb[dy * HP];
        s.x += v.x; s.y += v.y;
    }
    m[0] = make_float2(s.x * inv, s.y * inv);
#pragma unroll
    for (int j = 1; j < 4; ++j) {
        float2 a = hb[(j + 10) * HP], b = hb[(j - 1) * HP];
        s.x += a.x - b.x;
        s.y += a.y - b.y;
        m[j] = make_float2(s.x * inv, s.y * inv);
    }
}

// ---------------- K1: merged Xs (channel mean) + chi (+partial reductions) ----------------
__global__ void __launch_bounds__(256) k_xschi(
        const float* __restrict__ X, const float* __restrict__ G,
        float* __restrict__ Xs, float* __restrict__ chi,
        float* __restrict__ psum, float* __restrict__ pmin) {
    int t = threadIdx.x;
    if (blockIdx.x < 1024) {
        constexpr int HW4 = HW / 4;
        int i = blockIdx.x * 256 + t;
        int b = i / HW4, off = i - b * HW4;
        const float4* xp = (const float4*)(X + (size_t)b * Cn * HW) + off;
        float4 s = make_float4(0.f, 0.f, 0.f, 0.f);
#pragma unroll
        for (int c = 0; c < Cn; ++c) {
            float4 v = xp[(size_t)c * HW4];
            s.x += v.x; s.y += v.y; s.z += v.z; s.w += v.w;
        }
        const float sc = 1.0f / Cn;
        s.x *= sc; s.y *= sc; s.z *= sc; s.w *= sc;
        ((float4*)Xs)[i] = s;
        return;
    }
    __shared__ float ssum[256], smin[256];
    int bid = blockIdx.x - 1024;
    int base = bid * 1024;
    float ls = 0.f, lm = 1e30f;
#pragma unroll
    for (int k = 0; k < 4; ++k) {
        int p = base + t + k * 256;
        int off = p & (HW - 1);
        int y = off / Wn, x = off & (Wn - 1);
        float g = G[p];
        float gx = (x < Wn - 1) ? G[p + 1] - g : 0.f;
        float gy = (y < Hn - 1) ? G[p + Wn] - g : 0.f;
        float c = sqrtf(gx * gx + gy * gy + EPSC);
        chi[p] = c;
        ls += c;
        lm = fminf(lm, c);
    }
    ssum[t] = ls; smin[t] = lm;
    __syncthreads();
    for (int s = 128; s > 0; s >>= 1) {
        if (t < s) { ssum[t] += ssum[t + s]; smin[t] = fminf(smin[t], smin[t + s]); }
        __syncthreads();
    }
    if (t == 0) { psum[bid] = ssum[0]; pmin[bid] = smin[0]; }
}

// k_ssim hbox over 2 planes at pitch 49 (+3 offset), optionally squared
template <bool SQ>
__device__ __forceinline__ void ss_hbox2(const float* arrs, float* hs, int t) {
    if (t < 168) {
        int pl = t / 84, rem = t - pl * 84;
        int y = rem >> 1, xh = (rem & 1) << 4;
        const float* src = arrs + pl * SSZ + y * PW + xh + 3;
        float* hd = hs + pl * HSZ + y * HP + xh;
        float v = src[0];
        float s = SQ ? v * v : v;
#pragma unroll
        for (int dx = 1; dx < K; ++dx) { float u = src[dx]; s += SQ ? u * u : u; }
        hd[0] = s;
#pragma unroll
        for (int j = 1; j < 16; ++j) {
            float un = src[j + 10], uo = src[j - 1];
            s += (SQ ? un * un : un) - (SQ ? uo * uo : uo);
            hd[j] = s;
        }
    }
}

__device__ __forceinline__ void ss_vbox(const float* hs, int x, int r0, float m[4]) {
    const float inv_area = 1.f / (float)(K * K);
    const float* hb = hs + r0 * HP + x;
    float s = hb[0];
#pragma unroll
    for (int dy = 1; dy < K; ++dy) s += hb[dy * HP];
    m[0] = s * inv_area;
#pragma unroll
    for (int j = 1; j < 4; ++j) {
        s += hb[(j + 10) * HP] - hb[(j - 1) * HP];
        m[j] = s * inv_area;
    }
}

// ---------------- K3: merged ssim r=5 & r=1 + plane outputs + reductions ----------------
__global__ void __launch_bounds__(256) k_ssim(
        const float* __restrict__ Xs, const float* __restrict__ G,
        float* __restrict__ muG, float* __restrict__ varGr, float* __restrict__ taur,
        float* __restrict__ chig, float* __restrict__ nu,
        float* __restrict__ ps1, float* __restrict__ ps2) {
    __shared__ float arrs[2 * SSZ];   // x, g windows (pitch 49, 48-wide aligned)
    __shared__ float hs[2 * HSZ];
    float* red1 = hs;
    float* red2 = hs + HSZ;
    int t = threadIdx.x;
    int b = blockIdx.y;
    int tile = swz_tile(blockIdx.x);
    int tx0 = (tile % tiles_x) * TS, ty0 = (tile / tiles_x) * TS;
    const float* Xp = Xs + (size_t)b * HW;
    const float* Gp = G + (size_t)b * HW;
    for (int u = t; u < HALO * 12; u += 256) {
        int ly = u / 12, k = u - ly * 12;
        int gy = refl(ty0 - 5 + ly, Hn);
        int col = tx0 - 8 + 4 * k;
        int o = ly * PW + 4 * k;
        if (col >= 0 && col <= Wn - 4) {
            float4 xv = *(const float4*)(Xp + gy * Wn + col);
            float4 gv = *(const float4*)(Gp + gy * Wn + col);
            arrs[o] = xv.x; arrs[o + 1] = xv.y; arrs[o + 2] = xv.z; arrs[o + 3] = xv.w;
            arrs[SSZ + o] = gv.x; arrs[SSZ + o + 1] = gv.y;
            arrs[SSZ + o + 2] = gv.z; arrs[SSZ + o + 3] = gv.w;
        } else {
#pragma unroll
            for (int i = 0; i < 4; ++i) {
                int gx = refl(col + i, Wn);
                arrs[o + i] = Xp[gy * Wn + gx];
                arrs[SSZ + o + i] = Gp[gy * Wn + gx];
            }
        }
    }
    __syncthreads();

    int x = t & 31, g = t >> 5, r0 = g * 4;
    float acc[5][4];
    ss_hbox2<false>(arrs, hs, t);
    __syncthreads();
    ss_vbox(hs, x, r0, acc[0]);
    ss_vbox(hs + HSZ, x, r0, acc[1]);
    __syncthreads();
    ss_hbox2<true>(arrs, hs, t);
    __syncthreads();
    ss_vbox(hs, x, r0, acc[2]);
    ss_vbox(hs + HSZ, x, r0, acc[3]);
    __syncthreads();
    if (t < 168) {   // x*g plane, 8-wide chunks
        int y = t >> 2, c = t & 3;
        const float* sx = arrs + y * PW + 8 * c + 3;
        const float* sg = arrs + SSZ + y * PW + 8 * c + 3;
        float* hd = hs + y * HP + 8 * c;
        float s = sx[0] * sg[0];
#pragma unroll
        for (int dx = 1; dx < K; ++dx) s += sx[dx] * sg[dx];
        hd[0] = s;
#pragma unroll
        for (int j = 1; j < 8; ++j) {
            s += sx[j + 10] * sg[j + 10] - sx[j - 1] * sg[j - 1];
            hd[j] = s;
        }
    }
    __syncthreads();
    ss_vbox(hs, x, r0, acc[4]);

    float m1[5][4];
#pragma unroll
    for (int p = 0; p < 5; ++p) {
        float h3[6];
#pragma unroll
        for (int j = 0; j < 6; ++j) {
            int bb = (r0 + 4 + j) * PW + (x + 7);
            float s = 0.f;
#pragma unroll
            for (int i = 0; i < 3; ++i) {
                float vx = arrs[bb + i], vg = arrs[SSZ + bb + i];
                float v = (p == 0) ? vx : (p == 1) ? vg : (p == 2) ? vx * vx
                          : (p == 3) ? vg * vg : vx * vg;
                s += v;
            }
            h3[j] = s;
        }
#pragma unroll
        for (int j = 0; j < 4; ++j)
            m1[p][j] = (h3[j] + h3[j + 1] + h3[j + 2]) * (1.f / 9.f);
    }

    float l1 = 0.f, l2 = 0.f;
    float outv[5][4];
#pragma unroll
    for (int j = 0; j < 4; ++j) {
        float mux = acc[0][j], mug = acc[1][j], mxx = acc[2][j], mgg = acc[3][j], mxy = acc[4][j];
        float sx2 = fmaxf(mxx - mux * mux, 0.f);
        float sg2 = fmaxf(mgg - mug * mug, 0.f);
        float sxy = mxy - mux * mug;
        float num = (2.f * mux * mug + C1C) * (2.f * sxy + C2C);
        float den = (mux * mux + mug * mug + C1C) * (sx2 + sg2 + C2C);
        float tr_ = fminf(fmaxf((num / (den + DEN_EPS) + 1.f) * 0.5f, 0.f), 1.f);

        float n0 = m1[0][j], n1 = m1[1][j], n2 = m1[2][j], n3 = m1[3][j], n4 = m1[4][j];
        float sx21 = fmaxf(n2 - n0 * n0, 0.f);
        float sg21 = fmaxf(n3 - n1 * n1, 0.f);
        float sxy1 = n4 - n0 * n1;
        float num1 = (2.f * n0 * n1 + C1C) * (2.f * sxy1 + C2C);
        float den1 = (n0 * n0 + n1 * n1 + C1C) * (sx21 + sg21 + C2C);
        float t1_ = fminf(fmaxf((num1 / (den1 + DEN_EPS) + 1.f) * 0.5f, 0.f), 1.f);

        float chig_ = sqrtf(sg21 + EPSC) * sqrtf(sg2 + EPSC);
        float nu_ = fmaxf(t1_ * tr_, 0.f);
        outv[0][j] = mug; outv[1][j] = sg2; outv[2][j] = tr_;
        outv[3][j] = chig_; outv[4][j] = nu_;
        l1 += 1.f / (chig_ + EPSC);
        l2 += 1.f / (nu_ + THETAC);
    }
#pragma unroll
    for (int j = 0; j < 4; ++j) {
        int gp = b * HW + (ty0 + r0 + j) * Wn + (tx0 + x);
        muG[gp] = outv[0][j];
        varGr[gp] = outv[1][j];
        taur[gp] = outv[2][j];
        chig[gp] = outv[3][j];
        nu[gp] = outv[4][j];
    }
    __syncthreads();
    red1[t] = l1; red2[t] = l2;
    __syncthreads();
    for (int s = 128; s > 0; s >>= 1) {
        if (t < s) { red1[t] += red1[t + s]; red2[t] += red2[t + s]; }
        __syncthreads();
    }
    if (t == 0) {
        ps1[b * NT + blockIdx.x] = red1[0];
        ps2[b * NT + blockIdx.x] = red2[0];
    }
}

// ---------------- K red ----------------
__global__ void __launch_bounds__(256) k_red(
        const float* __restrict__ psum, const float* __restrict__ pmin,
        const float* __restrict__ s1, const float* __restrict__ s2,
        float* __restrict__ sc) {
    __shared__ float a1[256], a2[256];
    int t = threadIdx.x;
    if (blockIdx.x < 4) {
        int b = blockIdx.x;
        a1[t] = psum[b * 256 + t];
        a2[t] = pmin[b * 256 + t];
        __syncthreads();
        for (int s = 128; s > 0; s >>= 1) {
            if (t < s) { a1[t] += a1[t + s]; a2[t] = fminf(a2[t], a2[t + s]); }
            __syncthreads();
        }
        if (t == 0) {
            float mu = a1[0] / (float)HW;
            sc[b] = mu;
            sc[4 + b] = fmaxf(mu - a2[0], EPSC);
        }
    } else {
        int b = blockIdx.x - 4;
        a1[t] = s1[b * 256 + t];
        a2[t] = s2[b * 256 + t];
        __syncthreads();
        for (int s = 128; s > 0; s >>= 1) {
            if (t < s) { a1[t] += a1[t + s]; a2[t] += a2[t + s]; }
            __syncthreads();
        }
        if (t == 0) {
            sc[8 + b] = a1[0] / (float)HW;
            sc[12 + b] = a2[0] / (float)HW;
        }
    }
}

// ---------------- K4: packed (P, invD, muG) plane, 4-wide ----------------
__global__ void __launch_bounds__(256) k_pd(
        const float* __restrict__ chi, const float* __restrict__ chig,
        const float* __restrict__ nu, const float* __restrict__ taur,
        const float* __restrict__ vr, const float* __restrict__ muG,
        const float* __restrict__ sc, float4* __restrict__ PDM) {
    int i = blockIdx.x * 256 + threadIdx.x;
    int p0 = i * 4;
    int b = p0 >> 18;
    float mu = sc[b], eta = sc[4 + b], imc = sc[8 + b], imn = sc[12 + b];
    float4 c4 = ((const float4*)chi)[i];
    float4 cg4 = ((const float4*)chig)[i];
    float4 nu4 = ((const float4*)nu)[i];
    float4 tr4 = ((const float4*)taur)[i];
    float4 vr4 = ((const float4*)vr)[i];
    float4 mg4 = ((const float4*)muG)[i];
    float cc[4] = {c4.x, c4.y, c4.z, c4.w};
    float gg[4] = {cg4.x, cg4.y, cg4.z, cg4.w};
    float nn[4] = {nu4.x, nu4.y, nu4.z, nu4.w};
    float tt[4] = {tr4.x, tr4.y, tr4.z, tr4.w};
    float vv[4] = {vr4.x, vr4.y, vr4.z, vr4.w};
    float mm[4] = {mg4.x, mg4.y, mg4.z, mg4.w};
#pragma unroll
    for (int j = 0; j < 4; ++j) {
        float gamma = 1.f / (1.f + expf(-eta * (cc[j] - mu)));
        float GG = (gg[j] + EPSC) * imc;
        float w_e = 1.0f / (GG + EPSC);
        float GS = (nn[j] + THETAC) * imn;
        float w_s = gamma / (GS + EPSC);
        float P = w_e * gamma + w_s * tt[j];
        float D = vv[j] + EPSC + w_e + w_s + EPSC;
        PDM[p0 + j] = make_float4(P, 1.0f / D, mm[j], 0.f);
    }
}

// ---------------- K5: per-channel a,b (register hbox from global, 1 barrier) ----------------
__global__ void __launch_bounds__(256, 6) k_ab(
        const float* __restrict__ X, const float* __restrict__ G,
        const float4* __restrict__ PDM, unsigned int* __restrict__ AB) {
    __shared__ float2 h2[HSZ];           // (hsum X, hsum X*G), pitch 33
    int t = threadIdx.x;
    int pc = blockIdx.y, b = pc >> 4;
    int tile = swz_tile(blockIdx.x);
    int tx0 = (tile & 15) * TS, ty0 = (tile >> 4) * TS;
    int x = t & 31, wg = t >> 5, r0 = wg * 4;
    // prefetch epilogue operands (latency hides under hbox)
    const float4* Pp = PDM + (size_t)b * HW;
    int pbase = (ty0 + r0) * Wn + tx0 + x;
    float4 pdm[4];
#pragma unroll
    for (int j = 0; j < 4; ++j) pdm[j] = Pp[pbase + j * Wn];

    const float* Xp = X + (size_t)pc * HW;
    const float* Gp = G + (size_t)b * HW;
    // hbox tasks: 168 threads, row y, chunk c (8 outputs each), direct from global
    if (t < 168) {
        int y = t >> 2, c = t & 3;
        int gy = refl(ty0 - 5 + y, Hn);
        int col0 = tx0 + 8 * c - 8;      // 24-px window [col0, col0+24)
        const float* Xr = Xp + gy * Wn;
        const float* Gr = Gp + gy * Wn;
        float wx[24], wp[24];
        if (col0 >= 0 && col0 + 24 <= Wn) {
#pragma unroll
            for (int q = 0; q < 6; ++q) {
                float4 xv = *(const float4*)(Xr + col0 + 4 * q);
                float4 gv = *(const float4*)(Gr + col0 + 4 * q);
                wx[4 * q] = xv.x; wx[4 * q + 1] = xv.y; wx[4 * q + 2] = xv.z; wx[4 * q + 3] = xv.w;
                wp[4 * q] = xv.x * gv.x; wp[4 * q + 1] = xv.y * gv.y;
                wp[4 * q + 2] = xv.z * gv.z; wp[4 * q + 3] = xv.w * gv.w;
            }
        } else {
#pragma unroll
            for (int i = 0; i < 24; ++i) {
                int gx = refl(col0 + i, Wn);
                float xv = Xr[gx], gvv = Gr[gx];
                wx[i] = xv; wp[i] = xv * gvv;
            }
        }
        // output j taps wx[j+3 .. j+13]
        float2* hd = h2 + y * HP + 8 * c;
        float a0 = wx[3], a1 = wp[3];
#pragma unroll
        for (int d = 1; d < K; ++d) { a0 += wx[3 + d]; a1 += wp[3 + d]; }
        hd[0] = make_float2(a0, a1);
#pragma unroll
        for (int j = 1; j < 8; ++j) {
            a0 += wx[j + 13] - wx[j + 2];
            a1 += wp[j + 13] - wp[j + 2];
            hd[j] = make_float2(a0, a1);
        }
    }
    __syncthreads();

    float2 m[4];
    vbox4_2(h2, x, r0, m);

    unsigned int* Ap = AB + (size_t)pc * HW;
#pragma unroll
    for (int j = 0; j < 4; ++j) {
        float mx = m[j].x, mxg = m[j].y;
        float a = (mxg - pdm[j].z * mx + pdm[j].x) * pdm[j].y;  // *invD
        float bb = mx - a * pdm[j].z;
        Ap[pbase + j * Wn] = bf16pack(a, bb);
    }
}

// ---------------- K6: out = box11(a)*G + box11(b) (register hbox, 1 barrier) ----------------
__global__ void __launch_bounds__(256, 8) k_out(
        const unsigned int* __restrict__ AB, const float* __restrict__ G,
        float* __restrict__ out) {
    __shared__ float2 h2[HSZ];           // (hsum a, hsum b), pitch 33
    int t = threadIdx.x;
    int pc = blockIdx.y, b = pc >> 4;
    int tile = swz_tile(blockIdx.x);
    int tx0 = (tile & 15) * TS, ty0 = (tile >> 4) * TS;
    int x = t & 31, wg = t >> 5, r0 = wg * 4;
    // prefetch G for epilogue
    const float* Gp = G + (size_t)b * HW;
    int pbase = (ty0 + r0) * Wn + tx0 + x;
    float gv[4];
#pragma unroll
    for (int j = 0; j < 4; ++j) gv[j] = Gp[pbase + j * Wn];

    const unsigned int* Ap = AB + (size_t)pc * HW;
    if (t < 168) {
        int y = t >> 2, c = t & 3;
        int gy = refl(ty0 - 5 + y, Hn);
        int col0 = tx0 + 8 * c - 8;
        const unsigned int* Ar = Ap + gy * Wn;
        unsigned int w[24];
        if (col0 >= 0 && col0 + 24 <= Wn) {
#pragma unroll
            for (int q = 0; q < 6; ++q) {
                uint4 v = *(const uint4*)(Ar + col0 + 4 * q);
                w[4 * q] = v.x; w[4 * q + 1] = v.y; w[4 * q + 2] = v.z; w[4 * q + 3] = v.w;
            }
        } else {
#pragma unroll
            for (int i = 0; i < 24; ++i) w[i] = Ar[refl(col0 + i, Wn)];
        }
        float2* hd = h2 + y * HP + 8 * c;
        float a0 = bflo(w[3]), a1 = bfhi(w[3]);
#pragma unroll
        for (int d = 1; d < K; ++d) { a0 += bflo(w[3 + d]); a1 += bfhi(w[3 + d]); }
        hd[0] = make_float2(a0, a1);
#pragma unroll
        for (int j = 1; j < 8; ++j) {
            a0 += bflo(w[j + 13]) - bflo(w[j + 2]);
            a1 += bfhi(w[j + 13]) - bfhi(w[j + 2]);
            hd[j] = make_float2(a0, a1);
        }
    }
    __syncthreads();

    float2 m[4];
    vbox4_2(h2, x, r0, m);

    float* op = out + (size_t)pc * HW;
#pragma unroll
    for (int j = 0; j < 4; ++j)
        op[pbase + j * Wn] = m[j].x * gv[j] + m[j].y;
}

extern "C" void kernel_launch(void* const* d_in, const int* in_sizes, int n_in,
                              void* d_out, int out_size, void* d_ws, size_t ws_size,
                              hipStream_t stream) {
    const float* X = (const float*)d_in[0];
    const float* G = (const float*)d_in[1];
    float* out = (float*)d_out;
    float* ws = (float*)d_ws;

    float* Xs   = ws + 0 * (size_t)NP;
    float* chi  = ws + 1 * (size_t)NP;
    float* taur = ws + 2 * (size_t)NP;
    float* vr   = ws + 3 * (size_t)NP;
    float* muG  = ws + 4 * (size_t)NP;
    float* chig = ws + 5 * (size_t)NP;
    float* nu   = ws + 6 * (size_t)NP;
    float4* PDM = (float4*)(ws + 7 * (size_t)NP);            // 4*NP floats
    unsigned int* AB = (unsigned int*)(ws + 11 * (size_t)NP); // NX uints
    float* psum = ws + 43 * (size_t)NP;
    float* pmin = psum + 1024;
    float* ps1  = pmin + 1024;
    float* ps2  = ps1 + 1024;
    float* sc   = ps2 + 1024;   // 16 scalars

    dim3 blk(256);
    k_xschi<<<2048, blk, 0, stream>>>(X, G, Xs, chi, psum, pmin);

    dim3 gplane(NT, Bn);
    k_ssim<<<gplane, blk, 0, stream>>>(Xs, G, muG, vr, taur, chig, nu, ps1, ps2);
    k_red<<<8, blk, 0, stream>>>(psum, pmin, ps1, ps2, sc);
    k_pd<<<(NP / 4) / 256, blk, 0, stream>>>(chi, chig, nu, taur, vr, muG, sc, PDM);

    dim3 gchan(NT, Bn * Cn);
    k_ab<<<gchan, blk, 0, stream>>>(X, G, PDM, AB);
    k_out<<<gchan, blk, 0, stream>>>(AB, G, out);
}

// Round 14
// 109.692 us; speedup vs baseline: 1.3515x; 1.3515x over previous
//
#include <hip/hip_runtime.h>
#include <math.h>

#define EPSC 1e-6f
#define THETAC 1e-3f
#define C1C 1e-4f
#define C2C 9e-4f
#define DEN_EPS 1e-12f

constexpr int Bn = 4, Cn = 16, Hn = 512, Wn = 512;
constexpr int HW = Hn * Wn;          // 262144 = 2^18
constexpr int NP = Bn * HW;          // 1048576
constexpr int TS = 32, RAD = 5, K = 11;
constexpr int HALO = TS + 2 * RAD;   // 42
constexpr int HP = 33;               // horizontal-sum pitch (linear, conflict-free)
constexpr int HSZ = HALO * HP;       // 1386
constexpr int tiles_x = Wn / TS;     // 16
constexpr int NT = tiles_x * (Hn / TS); // 256

// 48-wide aligned window, pitch 49 (all tiled kernels)
constexpr int PW = 49;
constexpr int SSZ = HALO * PW;       // 2058

__device__ __forceinline__ int refl(int i, int n) {
    if (i < 0) i = -i;
    if (i >= n) i = 2 * n - 2 - i;
    return i;
}

__device__ __forceinline__ int swz_tile(int x) { return (x & 7) * (NT / 8) + (x >> 3); }

__device__ __forceinline__ unsigned int bf16pack(float a, float b) {
    unsigned int ua = __float_as_uint(a), ub = __float_as_uint(b);
    ua += 0x7FFFu + ((ua >> 16) & 1u);
    ub += 0x7FFFu + ((ub >> 16) & 1u);
    return (ua >> 16) | (ub & 0xFFFF0000u);
}
__device__ __forceinline__ float bflo(unsigned int v) { return __uint_as_float(v << 16); }
__device__ __forceinline__ float bfhi(unsigned int v) { return __uint_as_float(v & 0xFFFF0000u); }

// vbox4 over linear pitch-33 h
__device__ __forceinline__ void vbox4(const float* h, int x, int r0, float m[4]) {
    const float inv = 1.f / 121.f;
    const float* hb = h + r0 * HP + x;
    float s = hb[0];
#pragma unroll
    for (int dy = 1; dy < K; ++dy) s += hb[dy * HP];
    m[0] = s * inv;
#pragma unroll
    for (int j = 1; j < 4; ++j) {
        s += hb[(j + 10) * HP] - hb[(j - 1) * HP];
        m[j] = s * inv;
    }
}

// merged hbox over packed bf16-pair window: 168 tasks, both planes per read
__device__ __forceinline__ void hbox_packed(const unsigned int* su, float* h0, float* h1, int t) {
    if (t < 168) {
        int y = t >> 2, c = t & 3;
        const unsigned int* src = su + y * PW + 8 * c + 3;
        float* d0 = h0 + y * HP + 8 * c;
        float* d1 = h1 + y * HP + 8 * c;
        unsigned int u0 = src[0];
        float a0 = bflo(u0), a1 = bfhi(u0);
#pragma unroll
        for (int dx = 1; dx < K; ++dx) {
            unsigned int u = src[dx];
            a0 += bflo(u); a1 += bfhi(u);
        }
        d0[0] = a0; d1[0] = a1;
#pragma unroll
        for (int j = 1; j < 8; ++j) {
            unsigned int un = src[j + 10], uo = src[j - 1];
            a0 += bflo(un) - bflo(uo);
            a1 += bfhi(un) - bfhi(uo);
            d0[j] = a0; d1[j] = a1;
        }
    }
}

// ---------------- K1: Xs = channel mean (float4) ----------------
__global__ void __launch_bounds__(256) k_xs(
        const float* __restrict__ X, float* __restrict__ Xs) {
    constexpr int HW4 = HW / 4;
    int i = blockIdx.x * 256 + threadIdx.x;
    int b = i / HW4, off = i - b * HW4;
    const float4* xp = (const float4*)(X + (size_t)b * Cn * HW) + off;
    float4 s = make_float4(0.f, 0.f, 0.f, 0.f);
#pragma unroll
    for (int c = 0; c < Cn; ++c) {
        float4 v = xp[(size_t)c * HW4];
        s.x += v.x; s.y += v.y; s.z += v.z; s.w += v.w;
    }
    const float sc = 1.0f / Cn;
    s.x *= sc; s.y *= sc; s.z *= sc; s.w *= sc;
    ((float4*)Xs)[i] = s;
}

// k_ssim hbox over 2 planes at pitch 49 (+3 offset), optionally squared
template <bool SQ>
__device__ __forceinline__ void ss_hbox2(const float* arrs, float* hs, int t) {
    if (t < 168) {
        int pl = t / 84, rem = t - pl * 84;
        int y = rem >> 1, xh = (rem & 1) << 4;
        const float* src = arrs + pl * SSZ + y * PW + xh + 3;
        float* hd = hs + pl * HSZ + y * HP + xh;
        float v = src[0];
        float s = SQ ? v * v : v;
#pragma unroll
        for (int dx = 1; dx < K; ++dx) { float u = src[dx]; s += SQ ? u * u : u; }
        hd[0] = s;
#pragma unroll
        for (int j = 1; j < 16; ++j) {
            float un = src[j + 10], uo = src[j - 1];
            s += (SQ ? un * un : un) - (SQ ? uo * uo : uo);
            hd[j] = s;
        }
    }
}

__device__ __forceinline__ void ss_vbox(const float* hs, int x, int r0, float m[4]) {
    const float inv_area = 1.f / (float)(K * K);
    const float* hb = hs + r0 * HP + x;
    float s = hb[0];
#pragma unroll
    for (int dy = 1; dy < K; ++dy) s += hb[dy * HP];
    m[0] = s * inv_area;
#pragma unroll
    for (int j = 1; j < 4; ++j) {
        s += hb[(j + 10) * HP] - hb[(j - 1) * HP];
        m[j] = s * inv_area;
    }
}

// ---------------- K3: ssim r=5 & r=1 + chi + plane outputs + all tile reductions ----------------
__global__ void __launch_bounds__(256) k_ssim(
        const float* __restrict__ Xs, const float* __restrict__ G,
        float* __restrict__ muG, float* __restrict__ varGr, float* __restrict__ taur,
        float* __restrict__ chig, float* __restrict__ nu, float* __restrict__ chi,
        float* __restrict__ ps1, float* __restrict__ ps2,
        float* __restrict__ ps3, float* __restrict__ ps4) {
    __shared__ float arrs[2 * SSZ];   // x, g windows (pitch 49, 48-wide aligned)
    __shared__ float hs[2 * HSZ];
    float* red1 = hs;                 // aliased after last hs read
    float* red2 = hs + 256;
    float* red3 = hs + 512;
    float* red4 = hs + 768;
    int t = threadIdx.x;
    int b = blockIdx.y;
    int tile = swz_tile(blockIdx.x);
    int tx0 = (tile % tiles_x) * TS, ty0 = (tile / tiles_x) * TS;
    const float* Xp = Xs + (size_t)b * HW;
    const float* Gp = G + (size_t)b * HW;
    for (int u = t; u < HALO * 12; u += 256) {
        int ly = u / 12, k = u - ly * 12;
        int gy = refl(ty0 - 5 + ly, Hn);
        int col = tx0 - 8 + 4 * k;
        int o = ly * PW + 4 * k;
        if (col >= 0 && col <= Wn - 4) {
            float4 xv = *(const float4*)(Xp + gy * Wn + col);
            float4 gv = *(const float4*)(Gp + gy * Wn + col);
            arrs[o] = xv.x; arrs[o + 1] = xv.y; arrs[o + 2] = xv.z; arrs[o + 3] = xv.w;
            arrs[SSZ + o] = gv.x; arrs[SSZ + o + 1] = gv.y;
            arrs[SSZ + o + 2] = gv.z; arrs[SSZ + o + 3] = gv.w;
        } else {
#pragma unroll
            for (int i = 0; i < 4; ++i) {
                int gx = refl(col + i, Wn);
                arrs[o + i] = Xp[gy * Wn + gx];
                arrs[SSZ + o + i] = Gp[gy * Wn + gx];
            }
        }
    }
    __syncthreads();

    int x = t & 31, g = t >> 5, r0 = g * 4;
    float acc[5][4];
    ss_hbox2<false>(arrs, hs, t);
    __syncthreads();
    ss_vbox(hs, x, r0, acc[0]);
    ss_vbox(hs + HSZ, x, r0, acc[1]);
    __syncthreads();
    ss_hbox2<true>(arrs, hs, t);
    __syncthreads();
    ss_vbox(hs, x, r0, acc[2]);
    ss_vbox(hs + HSZ, x, r0, acc[3]);
    __syncthreads();
    if (t < 168) {   // x*g plane, 8-wide chunks
        int y = t >> 2, c = t & 3;
        const float* sx = arrs + y * PW + 8 * c + 3;
        const float* sg = arrs + SSZ + y * PW + 8 * c + 3;
        float* hd = hs + y * HP + 8 * c;
        float s = sx[0] * sg[0];
#pragma unroll
        for (int dx = 1; dx < K; ++dx) s += sx[dx] * sg[dx];
        hd[0] = s;
#pragma unroll
        for (int j = 1; j < 8; ++j) {
            s += sx[j + 10] * sg[j + 10] - sx[j - 1] * sg[j - 1];
            hd[j] = s;
        }
    }
    __syncthreads();
    ss_vbox(hs, x, r0, acc[4]);

    // r=1 box means + chi (from the G window, zero-pad forward diffs)
    float m1[5][4];
#pragma unroll
    for (int p = 0; p < 5; ++p) {
        float h3[6];
#pragma unroll
        for (int j = 0; j < 6; ++j) {
            int bb = (r0 + 4 + j) * PW + (x + 7);
            float s = 0.f;
#pragma unroll
            for (int i = 0; i < 3; ++i) {
                float vx = arrs[bb + i], vg = arrs[SSZ + bb + i];
                float v = (p == 0) ? vx : (p == 1) ? vg : (p == 2) ? vx * vx
                          : (p == 3) ? vg * vg : vx * vg;
                s += v;
            }
            h3[j] = s;
        }
#pragma unroll
        for (int j = 0; j < 4; ++j)
            m1[p][j] = (h3[j] + h3[j + 1] + h3[j + 2]) * (1.f / 9.f);
    }

    float chiv[4];
    float lsum = 0.f, lmin = 1e30f;
#pragma unroll
    for (int j = 0; j < 4; ++j) {
        int wr = r0 + j + 5, wc = x + 8;        // window coords of output px
        int px = tx0 + x, py = ty0 + r0 + j;    // global coords
        float gc = arrs[SSZ + wr * PW + wc];
        float gx = (px < Wn - 1) ? arrs[SSZ + wr * PW + wc + 1] - gc : 0.f;
        float gy = (py < Hn - 1) ? arrs[SSZ + (wr + 1) * PW + wc] - gc : 0.f;
        float c = sqrtf(gx * gx + gy * gy + EPSC);
        chiv[j] = c;
        lsum += c;
        lmin = fminf(lmin, c);
    }

    float l1 = 0.f, l2 = 0.f;
    float outv[5][4];
#pragma unroll
    for (int j = 0; j < 4; ++j) {
        float mux = acc[0][j], mug = acc[1][j], mxx = acc[2][j], mgg = acc[3][j], mxy = acc[4][j];
        float sx2 = fmaxf(mxx - mux * mux, 0.f);
        float sg2 = fmaxf(mgg - mug * mug, 0.f);
        float sxy = mxy - mux * mug;
        float num = (2.f * mux * mug + C1C) * (2.f * sxy + C2C);
        float den = (mux * mux + mug * mug + C1C) * (sx2 + sg2 + C2C);
        float tr_ = fminf(fmaxf((num / (den + DEN_EPS) + 1.f) * 0.5f, 0.f), 1.f);

        float n0 = m1[0][j], n1 = m1[1][j], n2 = m1[2][j], n3 = m1[3][j], n4 = m1[4][j];
        float sx21 = fmaxf(n2 - n0 * n0, 0.f);
        float sg21 = fmaxf(n3 - n1 * n1, 0.f);
        float sxy1 = n4 - n0 * n1;
        float num1 = (2.f * n0 * n1 + C1C) * (2.f * sxy1 + C2C);
        float den1 = (n0 * n0 + n1 * n1 + C1C) * (sx21 + sg21 + C2C);
        float t1_ = fminf(fmaxf((num1 / (den1 + DEN_EPS) + 1.f) * 0.5f, 0.f), 1.f);

        float chig_ = sqrtf(sg21 + EPSC) * sqrtf(sg2 + EPSC);
        float nu_ = fmaxf(t1_ * tr_, 0.f);
        outv[0][j] = mug; outv[1][j] = sg2; outv[2][j] = tr_;
        outv[3][j] = chig_; outv[4][j] = nu_;
        l1 += 1.f / (chig_ + EPSC);
        l2 += 1.f / (nu_ + THETAC);
    }
#pragma unroll
    for (int j = 0; j < 4; ++j) {
        int gp = b * HW + (ty0 + r0 + j) * Wn + (tx0 + x);
        muG[gp] = outv[0][j];
        varGr[gp] = outv[1][j];
        taur[gp] = outv[2][j];
        chig[gp] = outv[3][j];
        nu[gp] = outv[4][j];
        chi[gp] = chiv[j];
    }
    __syncthreads();   // hs reads done; safe to alias red arrays
    red1[t] = l1; red2[t] = l2; red3[t] = lsum; red4[t] = lmin;
    __syncthreads();
    for (int s = 128; s > 0; s >>= 1) {
        if (t < s) {
            red1[t] += red1[t + s];
            red2[t] += red2[t + s];
            red3[t] += red3[t + s];
            red4[t] = fminf(red4[t], red4[t + s]);
        }
        __syncthreads();
    }
    if (t == 0) {
        ps1[b * NT + blockIdx.x] = red1[0];
        ps2[b * NT + blockIdx.x] = red2[0];
        ps3[b * NT + blockIdx.x] = red3[0];
        ps4[b * NT + blockIdx.x] = red4[0];
    }
}

// ---------------- K red: all 4 global reductions ----------------
__global__ void __launch_bounds__(256) k_red(
        const float* __restrict__ ps1, const float* __restrict__ ps2,
        const float* __restrict__ ps3, const float* __restrict__ ps4,
        float* __restrict__ sc) {
    __shared__ float a1[256], a2[256];
    int t = threadIdx.x;
    if (blockIdx.x < 4) {
        int b = blockIdx.x;
        a1[t] = ps3[b * 256 + t];
        a2[t] = ps4[b * 256 + t];
        __syncthreads();
        for (int s = 128; s > 0; s >>= 1) {
            if (t < s) { a1[t] += a1[t + s]; a2[t] = fminf(a2[t], a2[t + s]); }
            __syncthreads();
        }
        if (t == 0) {
            float mu = a1[0] / (float)HW;
            sc[b] = mu;
            sc[4 + b] = fmaxf(mu - a2[0], EPSC);
        }
    } else {
        int b = blockIdx.x - 4;
        a1[t] = ps1[b * 256 + t];
        a2[t] = ps2[b * 256 + t];
        __syncthreads();
        for (int s = 128; s > 0; s >>= 1) {
            if (t < s) { a1[t] += a1[t + s]; a2[t] += a2[t + s]; }
            __syncthreads();
        }
        if (t == 0) {
            sc[8 + b] = a1[0] / (float)HW;
            sc[12 + b] = a2[0] / (float)HW;
        }
    }
}

// ---------------- K4: packed (P, invD, muG) plane, 4-wide ----------------
__global__ void __launch_bounds__(256) k_pd(
        const float* __restrict__ chi, const float* __restrict__ chig,
        const float* __restrict__ nu, const float* __restrict__ taur,
        const float* __restrict__ vr, const float* __restrict__ muG,
        const float* __restrict__ sc, float4* __restrict__ PDM) {
    int i = blockIdx.x * 256 + threadIdx.x;
    int p0 = i * 4;
    int b = p0 >> 18;
    float mu = sc[b], eta = sc[4 + b], imc = sc[8 + b], imn = sc[12 + b];
    float4 c4 = ((const float4*)chi)[i];
    float4 cg4 = ((const float4*)chig)[i];
    float4 nu4 = ((const float4*)nu)[i];
    float4 tr4 = ((const float4*)taur)[i];
    float4 vr4 = ((const float4*)vr)[i];
    float4 mg4 = ((const float4*)muG)[i];
    float cc[4] = {c4.x, c4.y, c4.z, c4.w};
    float gg[4] = {cg4.x, cg4.y, cg4.z, cg4.w};
    float nn[4] = {nu4.x, nu4.y, nu4.z, nu4.w};
    float tt[4] = {tr4.x, tr4.y, tr4.z, tr4.w};
    float vv[4] = {vr4.x, vr4.y, vr4.z, vr4.w};
    float mm[4] = {mg4.x, mg4.y, mg4.z, mg4.w};
#pragma unroll
    for (int j = 0; j < 4; ++j) {
        float gamma = 1.f / (1.f + expf(-eta * (cc[j] - mu)));
        float GG = (gg[j] + EPSC) * imc;
        float w_e = 1.0f / (GG + EPSC);
        float GS = (nn[j] + THETAC) * imn;
        float w_s = gamma / (GS + EPSC);
        float P = w_e * gamma + w_s * tt[j];
        float D = vv[j] + EPSC + w_e + w_s + EPSC;
        PDM[p0 + j] = make_float4(P, 1.0f / D, mm[j], 0.f);
    }
}

// ---------------- K5: per-channel a,b (packed bf16 window, 2 barriers) ----------------
__global__ void __launch_bounds__(256) k_ab(
        const float* __restrict__ X, const float* __restrict__ G,
        const float4* __restrict__ PDM, unsigned int* __restrict__ AB) {
    __shared__ unsigned int su[SSZ];     // packed (X, X*G) bf16 pairs, pitch 49
    __shared__ float h0[HSZ], h1[HSZ];
    int t = threadIdx.x;
    int pc = blockIdx.y, b = pc >> 4;
    int tile = swz_tile(blockIdx.x);
    int tx0 = (tile & 15) * TS, ty0 = (tile >> 4) * TS;
    int x = t & 31, wg = t >> 5, r0 = wg * 4;

    const float* Xp = X + (size_t)pc * HW;
    const float* Gp = G + (size_t)b * HW;
    // unified staging: per-chunk validity, vec4 fast path; pack (X, X*G) -> bf16 pair
    for (int u = t; u < HALO * 12; u += 256) {
        int ly = u / 12, k = u - ly * 12;
        int gy = refl(ty0 - 5 + ly, Hn);
        int col = tx0 - 8 + 4 * k;
        int o = ly * PW + 4 * k;
        if (col >= 0 && col <= Wn - 4) {
            float4 xv = *(const float4*)(Xp + gy * Wn + col);
            float4 gv = *(const float4*)(Gp + gy * Wn + col);
            su[o]     = bf16pack(xv.x, xv.x * gv.x);
            su[o + 1] = bf16pack(xv.y, xv.y * gv.y);
            su[o + 2] = bf16pack(xv.z, xv.z * gv.z);
            su[o + 3] = bf16pack(xv.w, xv.w * gv.w);
        } else {
#pragma unroll
            for (int i = 0; i < 4; ++i) {
                int gx = refl(col + i, Wn);
                float xv = Xp[gy * Wn + gx], gv = Gp[gy * Wn + gx];
                su[o + i] = bf16pack(xv, xv * gv);
            }
        }
    }
    __syncthreads();
    hbox_packed(su, h0, h1, t);   // h0 = hsum(X), h1 = hsum(X*G)
    __syncthreads();

    float mx[4], mxg[4];
    vbox4(h0, x, r0, mx);
    vbox4(h1, x, r0, mxg);

    // epilogue operand loads (PDM is L3-resident; latency hidden by occupancy)
    const float4* Pp = PDM + (size_t)b * HW;
    int pbase = (ty0 + r0) * Wn + tx0 + x;
    unsigned int* Ap = AB + (size_t)pc * HW;
#pragma unroll
    for (int j = 0; j < 4; ++j) {
        float4 pdm = Pp[pbase + j * Wn];
        float a = (mxg[j] - pdm.z * mx[j] + pdm.x) * pdm.y;  // *invD
        float bb = mx[j] - a * pdm.z;
        Ap[pbase + j * Wn] = bf16pack(a, bb);
    }
}

// ---------------- K6: out = box11(a)*G + box11(b) (packed su, 2 barriers) ----------------
__global__ void __launch_bounds__(256) k_out(
        const unsigned int* __restrict__ AB, const float* __restrict__ G,
        float* __restrict__ out) {
    __shared__ unsigned int su[SSZ];     // packed (a,b), pitch 49
    __shared__ float h0[HSZ], h1[HSZ];
    int t = threadIdx.x;
    int pc = blockIdx.y, b = pc >> 4;
    int tile = swz_tile(blockIdx.x);
    int tx0 = (tile & 15) * TS, ty0 = (tile >> 4) * TS;
    int x = t & 31, wg = t >> 5, r0 = wg * 4;

    const unsigned int* Ap = AB + (size_t)pc * HW;
    for (int u = t; u < HALO * 12; u += 256) {
        int ly = u / 12, k = u - ly * 12;
        int gy = refl(ty0 - 5 + ly, Hn);
        int col = tx0 - 8 + 4 * k;
        int o = ly * PW + 4 * k;
        if (col >= 0 && col <= Wn - 4) {
            uint4 v = *(const uint4*)(Ap + gy * Wn + col);
            su[o] = v.x; su[o + 1] = v.y; su[o + 2] = v.z; su[o + 3] = v.w;
        } else {
#pragma unroll
            for (int i = 0; i < 4; ++i) {
                int gx = refl(col + i, Wn);
                su[o + i] = Ap[gy * Wn + gx];
            }
        }
    }
    __syncthreads();
    hbox_packed(su, h0, h1, t);   // h0 = hsum(a), h1 = hsum(b)
    __syncthreads();

    float ma[4], mb[4];
    vbox4(h0, x, r0, ma);
    vbox4(h1, x, r0, mb);

    // epilogue G loads (G is L2-resident across 16 channels)
    const float* Gp = G + (size_t)b * HW;
    int pbase = (ty0 + r0) * Wn + tx0 + x;
    float* op = out + (size_t)pc * HW;
#pragma unroll
    for (int j = 0; j < 4; ++j)
        op[pbase + j * Wn] = ma[j] * Gp[pbase + j * Wn] + mb[j];
}

extern "C" void kernel_launch(void* const* d_in, const int* in_sizes, int n_in,
                              void* d_out, int out_size, void* d_ws, size_t ws_size,
                              hipStream_t stream) {
    const float* X = (const float*)d_in[0];
    const float* G = (const float*)d_in[1];
    float* out = (float*)d_out;
    float* ws = (float*)d_ws;

    float* Xs   = ws + 0 * (size_t)NP;
    float* chi  = ws + 1 * (size_t)NP;
    float* taur = ws + 2 * (size_t)NP;
    float* vr   = ws + 3 * (size_t)NP;
    float* muG  = ws + 4 * (size_t)NP;
    float* chig = ws + 5 * (size_t)NP;
    float* nu   = ws + 6 * (size_t)NP;
    float4* PDM = (float4*)(ws + 7 * (size_t)NP);            // 4*NP floats
    unsigned int* AB = (unsigned int*)(ws + 11 * (size_t)NP); // NX uints
    float* ps1  = ws + 43 * (size_t)NP;
    float* ps2  = ps1 + 1024;
    float* ps3  = ps2 + 1024;
    float* ps4  = ps3 + 1024;
    float* sc   = ps4 + 1024;   // 16 scalars

    dim3 blk(256);
    k_xs<<<(NP / 4) / 256, blk, 0, stream>>>(X, Xs);

    dim3 gplane(NT, Bn);
    k_ssim<<<gplane, blk, 0, stream>>>(Xs, G, muG, vr, taur, chig, nu, chi,
                                       ps1, ps2, ps3, ps4);
    k_red<<<8, blk, 0, stream>>>(ps1, ps2, ps3, ps4, sc);
    k_pd<<<(NP / 4) / 256, blk, 0, stream>>>(chi, chig, nu, taur, vr, muG, sc, PDM);

    dim3 gchan(NT, Bn * Cn);
    k_ab<<<gchan, blk, 0, stream>>>(X, G, PDM, AB);
    k_out<<<gchan, blk, 0, stream>>>(AB, G, out);
}

// Round 16
// 107.606 us; speedup vs baseline: 1.3777x; 1.0194x over previous
//
#include <hip/hip_runtime.h>
#include <math.h>

#define EPSC 1e-6f
#define THETAC 1e-3f
#define C1C 1e-4f
#define C2C 9e-4f
#define DEN_EPS 1e-12f

constexpr int Bn = 4, Cn = 16, Hn = 512, Wn = 512;
constexpr int HW = Hn * Wn;          // 262144 = 2^18
constexpr int NP = Bn * HW;          // 1048576
constexpr int TS = 32, RAD = 5, K = 11;
constexpr int HALO = TS + 2 * RAD;   // 42
constexpr int HP = 33;               // horizontal-sum pitch (linear, conflict-free)
constexpr int HSZ = HALO * HP;       // 1386
constexpr int tiles_x = Wn / TS;     // 16
constexpr int NT = tiles_x * (Hn / TS); // 256

// 48-wide aligned window, pitch 49 (all tiled kernels)
constexpr int PW = 49;
constexpr int SSZ = HALO * PW;       // 2058

typedef __fp16 h2 __attribute__((ext_vector_type(2)));

__device__ __forceinline__ int refl(int i, int n) {
    if (i < 0) i = -i;
    if (i >= n) i = 2 * n - 2 - i;
    return i;
}

__device__ __forceinline__ int swz_tile(int x) { return (x & 7) * (NT / 8) + (x >> 3); }

__device__ __forceinline__ h2 u2h(unsigned int u) { return __builtin_bit_cast(h2, u); }

// merged hbox over packed fp16-pair window: 168 tasks, packed v_pk_add_f16
__device__ __forceinline__ void hbox_h2(const h2* su, h2* hd_arr, int t) {
    if (t < 168) {
        int y = t >> 2, c = t & 3;
        const h2* src = su + y * PW + 8 * c + 3;
        h2* d = hd_arr + y * HP + 8 * c;
        h2 s = src[0];
#pragma unroll
        for (int dx = 1; dx < K; ++dx) s = s + src[dx];
        d[0] = s;
#pragma unroll
        for (int j = 1; j < 8; ++j) {
            s = s + src[j + 10] - src[j - 1];
            d[j] = s;
        }
    }
}

// vbox4 over packed fp16 h: packed accumulate, unpack at the end
__device__ __forceinline__ void vbox4_h2(const h2* h, int x, int r0, float2 m[4]) {
    const float inv = 1.f / 121.f;
    const h2* hb = h + r0 * HP + x;
    h2 s = hb[0];
#pragma unroll
    for (int dy = 1; dy < K; ++dy) s = s + hb[dy * HP];
    m[0] = make_float2((float)s.x * inv, (float)s.y * inv);
#pragma unroll
    for (int j = 1; j < 4; ++j) {
        s = s + hb[(j + 10) * HP] - hb[(j - 1) * HP];
        m[j] = make_float2((float)s.x * inv, (float)s.y * inv);
    }
}

// ---------------- K1: Xs = channel mean (float4) ----------------
__global__ void __launch_bounds__(256) k_xs(
        const float* __restrict__ X, float* __restrict__ Xs) {
    constexpr int HW4 = HW / 4;
    int i = blockIdx.x * 256 + threadIdx.x;
    int b = i / HW4, off = i - b * HW4;
    const float4* xp = (const float4*)(X + (size_t)b * Cn * HW) + off;
    float4 s = make_float4(0.f, 0.f, 0.f, 0.f);
#pragma unroll
    for (int c = 0; c < Cn; ++c) {
        float4 v = xp[(size_t)c * HW4];
        s.x += v.x; s.y += v.y; s.z += v.z; s.w += v.w;
    }
    const float sc = 1.0f / Cn;
    s.x *= sc; s.y *= sc; s.z *= sc; s.w *= sc;
    ((float4*)Xs)[i] = s;
}

// k_ssim hbox over 2 planes at pitch 49 (+3 offset), optionally squared
template <bool SQ>
__device__ __forceinline__ void ss_hbox2(const float* arrs, float* hs, int t) {
    if (t < 168) {
        int pl = t / 84, rem = t - pl * 84;
        int y = rem >> 1, xh = (rem & 1) << 4;
        const float* src = arrs + pl * SSZ + y * PW + xh + 3;
        float* hd = hs + pl * HSZ + y * HP + xh;
        float v = src[0];
        float s = SQ ? v * v : v;
#pragma unroll
        for (int dx = 1; dx < K; ++dx) { float u = src[dx]; s += SQ ? u * u : u; }
        hd[0] = s;
#pragma unroll
        for (int j = 1; j < 16; ++j) {
            float un = src[j + 10], uo = src[j - 1];
            s += (SQ ? un * un : un) - (SQ ? uo * uo : uo);
            hd[j] = s;
        }
    }
}

__device__ __forceinline__ void ss_vbox(const float* hs, int x, int r0, float m[4]) {
    const float inv_area = 1.f / (float)(K * K);
    const float* hb = hs + r0 * HP + x;
    float s = hb[0];
#pragma unroll
    for (int dy = 1; dy < K; ++dy) s += hb[dy * HP];
    m[0] = s * inv_area;
#pragma unroll
    for (int j = 1; j < 4; ++j) {
        s += hb[(j + 10) * HP] - hb[(j - 1) * HP];
        m[j] = s * inv_area;
    }
}

// ---------------- K3: ssim r=5 & r=1 + chi + plane outputs + all tile reductions ----------------
__global__ void __launch_bounds__(256) k_ssim(
        const float* __restrict__ Xs, const float* __restrict__ G,
        float* __restrict__ muG, float* __restrict__ varGr, float* __restrict__ taur,
        float* __restrict__ chig, float* __restrict__ nu, float* __restrict__ chi,
        float* __restrict__ ps1, float* __restrict__ ps2,
        float* __restrict__ ps3, float* __restrict__ ps4) {
    __shared__ float arrs[2 * SSZ];   // x, g windows (pitch 49, 48-wide aligned)
    __shared__ float hs[2 * HSZ];
    float* red1 = hs;                 // aliased after last hs read
    float* red2 = hs + 256;
    float* red3 = hs + 512;
    float* red4 = hs + 768;
    int t = threadIdx.x;
    int b = blockIdx.y;
    int tile = swz_tile(blockIdx.x);
    int tx0 = (tile % tiles_x) * TS, ty0 = (tile / tiles_x) * TS;
    const float* Xp = Xs + (size_t)b * HW;
    const float* Gp = G + (size_t)b * HW;
    for (int u = t; u < HALO * 12; u += 256) {
        int ly = u / 12, k = u - ly * 12;
        int gy = refl(ty0 - 5 + ly, Hn);
        int col = tx0 - 8 + 4 * k;
        int o = ly * PW + 4 * k;
        if (col >= 0 && col <= Wn - 4) {
            float4 xv = *(const float4*)(Xp + gy * Wn + col);
            float4 gv = *(const float4*)(Gp + gy * Wn + col);
            arrs[o] = xv.x; arrs[o + 1] = xv.y; arrs[o + 2] = xv.z; arrs[o + 3] = xv.w;
            arrs[SSZ + o] = gv.x; arrs[SSZ + o + 1] = gv.y;
            arrs[SSZ + o + 2] = gv.z; arrs[SSZ + o + 3] = gv.w;
        } else {
#pragma unroll
            for (int i = 0; i < 4; ++i) {
                int gx = refl(col + i, Wn);
                arrs[o + i] = Xp[gy * Wn + gx];
                arrs[SSZ + o + i] = Gp[gy * Wn + gx];
            }
        }
    }
    __syncthreads();

    int x = t & 31, g = t >> 5, r0 = g * 4;
    float acc[5][4];
    ss_hbox2<false>(arrs, hs, t);
    __syncthreads();
    ss_vbox(hs, x, r0, acc[0]);
    ss_vbox(hs + HSZ, x, r0, acc[1]);
    __syncthreads();
    ss_hbox2<true>(arrs, hs, t);
    __syncthreads();
    ss_vbox(hs, x, r0, acc[2]);
    ss_vbox(hs + HSZ, x, r0, acc[3]);
    __syncthreads();
    if (t < 168) {   // x*g plane, 8-wide chunks
        int y = t >> 2, c = t & 3;
        const float* sx = arrs + y * PW + 8 * c + 3;
        const float* sg = arrs + SSZ + y * PW + 8 * c + 3;
        float* hd = hs + y * HP + 8 * c;
        float s = sx[0] * sg[0];
#pragma unroll
        for (int dx = 1; dx < K; ++dx) s += sx[dx] * sg[dx];
        hd[0] = s;
#pragma unroll
        for (int j = 1; j < 8; ++j) {
            s += sx[j + 10] * sg[j + 10] - sx[j - 1] * sg[j - 1];
            hd[j] = s;
        }
    }
    __syncthreads();
    ss_vbox(hs, x, r0, acc[4]);

    // r=1 box means + chi (from the G window, zero-pad forward diffs)
    float m1[5][4];
#pragma unroll
    for (int p = 0; p < 5; ++p) {
        float h3[6];
#pragma unroll
        for (int j = 0; j < 6; ++j) {
            int bb = (r0 + 4 + j) * PW + (x + 7);
            float s = 0.f;
#pragma unroll
            for (int i = 0; i < 3; ++i) {
                float vx = arrs[bb + i], vg = arrs[SSZ + bb + i];
                float v = (p == 0) ? vx : (p == 1) ? vg : (p == 2) ? vx * vx
                          : (p == 3) ? vg * vg : vx * vg;
                s += v;
            }
            h3[j] = s;
        }
#pragma unroll
        for (int j = 0; j < 4; ++j)
            m1[p][j] = (h3[j] + h3[j + 1] + h3[j + 2]) * (1.f / 9.f);
    }

    float chiv[4];
    float lsum = 0.f, lmin = 1e30f;
#pragma unroll
    for (int j = 0; j < 4; ++j) {
        int wr = r0 + j + 5, wc = x + 8;        // window coords of output px
        int px = tx0 + x, py = ty0 + r0 + j;    // global coords
        float gc = arrs[SSZ + wr * PW + wc];
        float gx = (px < Wn - 1) ? arrs[SSZ + wr * PW + wc + 1] - gc : 0.f;
        float gy = (py < Hn - 1) ? arrs[SSZ + (wr + 1) * PW + wc] - gc : 0.f;
        float c = sqrtf(gx * gx + gy * gy + EPSC);
        chiv[j] = c;
        lsum += c;
        lmin = fminf(lmin, c);
    }

    float l1 = 0.f, l2 = 0.f;
    float outv[5][4];
#pragma unroll
    for (int j = 0; j < 4; ++j) {
        float mux = acc[0][j], mug = acc[1][j], mxx = acc[2][j], mgg = acc[3][j], mxy = acc[4][j];
        float sx2 = fmaxf(mxx - mux * mux, 0.f);
        float sg2 = fmaxf(mgg - mug * mug, 0.f);
        float sxy = mxy - mux * mug;
        float num = (2.f * mux * mug + C1C) * (2.f * sxy + C2C);
        float den = (mux * mux + mug * mug + C1C) * (sx2 + sg2 + C2C);
        float tr_ = fminf(fmaxf((num / (den + DEN_EPS) + 1.f) * 0.5f, 0.f), 1.f);

        float n0 = m1[0][j], n1 = m1[1][j], n2 = m1[2][j], n3 = m1[3][j], n4 = m1[4][j];
        float sx21 = fmaxf(n2 - n0 * n0, 0.f);
        float sg21 = fmaxf(n3 - n1 * n1, 0.f);
        float sxy1 = n4 - n0 * n1;
        float num1 = (2.f * n0 * n1 + C1C) * (2.f * sxy1 + C2C);
        float den1 = (n0 * n0 + n1 * n1 + C1C) * (sx21 + sg21 + C2C);
        float t1_ = fminf(fmaxf((num1 / (den1 + DEN_EPS) + 1.f) * 0.5f, 0.f), 1.f);

        float chig_ = sqrtf(sg21 + EPSC) * sqrtf(sg2 + EPSC);
        float nu_ = fmaxf(t1_ * tr_, 0.f);
        outv[0][j] = mug; outv[1][j] = sg2; outv[2][j] = tr_;
        outv[3][j] = chig_; outv[4][j] = nu_;
        l1 += 1.f / (chig_ + EPSC);
        l2 += 1.f / (nu_ + THETAC);
    }
#pragma unroll
    for (int j = 0; j < 4; ++j) {
        int gp = b * HW + (ty0 + r0 + j) * Wn + (tx0 + x);
        muG[gp] = outv[0][j];
        varGr[gp] = outv[1][j];
        taur[gp] = outv[2][j];
        chig[gp] = outv[3][j];
        nu[gp] = outv[4][j];
        chi[gp] = chiv[j];
    }
    __syncthreads();   // hs reads done; safe to alias red arrays
    red1[t] = l1; red2[t] = l2; red3[t] = lsum; red4[t] = lmin;
    __syncthreads();
    for (int s = 128; s > 0; s >>= 1) {
        if (t < s) {
            red1[t] += red1[t + s];
            red2[t] += red2[t + s];
            red3[t] += red3[t + s];
            red4[t] = fminf(red4[t], red4[t + s]);
        }
        __syncthreads();
    }
    if (t == 0) {
        ps1[b * NT + blockIdx.x] = red1[0];
        ps2[b * NT + blockIdx.x] = red2[0];
        ps3[b * NT + blockIdx.x] = red3[0];
        ps4[b * NT + blockIdx.x] = red4[0];
    }
}

// ---------------- K red: all 4 global reductions ----------------
__global__ void __launch_bounds__(256) k_red(
        const float* __restrict__ ps1, const float* __restrict__ ps2,
        const float* __restrict__ ps3, const float* __restrict__ ps4,
        float* __restrict__ sc) {
    __shared__ float a1[256], a2[256];
    int t = threadIdx.x;
    if (blockIdx.x < 4) {
        int b = blockIdx.x;
        a1[t] = ps3[b * 256 + t];
        a2[t] = ps4[b * 256 + t];
        __syncthreads();
        for (int s = 128; s > 0; s >>= 1) {
            if (t < s) { a1[t] += a1[t + s]; a2[t] = fminf(a2[t], a2[t + s]); }
            __syncthreads();
        }
        if (t == 0) {
            float mu = a1[0] / (float)HW;
            sc[b] = mu;
            sc[4 + b] = fmaxf(mu - a2[0], EPSC);
        }
    } else {
        int b = blockIdx.x - 4;
        a1[t] = ps1[b * 256 + t];
        a2[t] = ps2[b * 256 + t];
        __syncthreads();
        for (int s = 128; s > 0; s >>= 1) {
            if (t < s) { a1[t] += a1[t + s]; a2[t] += a2[t + s]; }
            __syncthreads();
        }
        if (t == 0) {
            sc[8 + b] = a1[0] / (float)HW;
            sc[12 + b] = a2[0] / (float)HW;
        }
    }
}

// ---------------- K4: packed (P, invD, muG) plane, 4-wide ----------------
__global__ void __launch_bounds__(256) k_pd(
        const float* __restrict__ chi, const float* __restrict__ chig,
        const float* __restrict__ nu, const float* __restrict__ taur,
        const float* __restrict__ vr, const float* __restrict__ muG,
        const float* __restrict__ sc, float4* __restrict__ PDM) {
    int i = blockIdx.x * 256 + threadIdx.x;
    int p0 = i * 4;
    int b = p0 >> 18;
    float mu = sc[b], eta = sc[4 + b], imc = sc[8 + b], imn = sc[12 + b];
    float4 c4 = ((const float4*)chi)[i];
    float4 cg4 = ((const float4*)chig)[i];
    float4 nu4 = ((const float4*)nu)[i];
    float4 tr4 = ((const float4*)taur)[i];
    float4 vr4 = ((const float4*)vr)[i];
    float4 mg4 = ((const float4*)muG)[i];
    float cc[4] = {c4.x, c4.y, c4.z, c4.w};
    float gg[4] = {cg4.x, cg4.y, cg4.z, cg4.w};
    float nn[4] = {nu4.x, nu4.y, nu4.z, nu4.w};
    float tt[4] = {tr4.x, tr4.y, tr4.z, tr4.w};
    float vv[4] = {vr4.x, vr4.y, vr4.z, vr4.w};
    float mm[4] = {mg4.x, mg4.y, mg4.z, mg4.w};
#pragma unroll
    for (int j = 0; j < 4; ++j) {
        float gamma = 1.f / (1.f + expf(-eta * (cc[j] - mu)));
        float GG = (gg[j] + EPSC) * imc;
        float w_e = 1.0f / (GG + EPSC);
        float GS = (nn[j] + THETAC) * imn;
        float w_s = gamma / (GS + EPSC);
        float P = w_e * gamma + w_s * tt[j];
        float D = vv[j] + EPSC + w_e + w_s + EPSC;
        PDM[p0 + j] = make_float4(P, 1.0f / D, mm[j], 0.f);
    }
}

// ---------------- K5: per-channel a,b (packed fp16 window, pk math, 2 barriers) ----------------
__global__ void __launch_bounds__(256) k_ab(
        const float* __restrict__ X, const float* __restrict__ G,
        const float4* __restrict__ PDM, h2* __restrict__ AB) {
    __shared__ h2 su[SSZ];     // packed (X, X*G) fp16 pairs, pitch 49
    __shared__ h2 hx[HSZ];     // packed (hsum X, hsum X*G)
    int t = threadIdx.x;
    int pc = blockIdx.y, b = pc >> 4;
    int tile = swz_tile(blockIdx.x);
    int tx0 = (tile & 15) * TS, ty0 = (tile >> 4) * TS;
    int x = t & 31, wg = t >> 5, r0 = wg * 4;

    const float* Xp = X + (size_t)pc * HW;
    const float* Gp = G + (size_t)b * HW;
    // unified staging: per-chunk validity, vec4 fast path; pack (X, X*G) -> fp16 pair (1 op)
    for (int u = t; u < HALO * 12; u += 256) {
        int ly = u / 12, k = u - ly * 12;
        int gy = refl(ty0 - 5 + ly, Hn);
        int col = tx0 - 8 + 4 * k;
        int o = ly * PW + 4 * k;
        if (col >= 0 && col <= Wn - 4) {
            float4 xv = *(const float4*)(Xp + gy * Wn + col);
            float4 gv = *(const float4*)(Gp + gy * Wn + col);
            su[o]     = __builtin_amdgcn_cvt_pkrtz(xv.x, xv.x * gv.x);
            su[o + 1] = __builtin_amdgcn_cvt_pkrtz(xv.y, xv.y * gv.y);
            su[o + 2] = __builtin_amdgcn_cvt_pkrtz(xv.z, xv.z * gv.z);
            su[o + 3] = __builtin_amdgcn_cvt_pkrtz(xv.w, xv.w * gv.w);
        } else {
#pragma unroll
            for (int i = 0; i < 4; ++i) {
                int gx = refl(col + i, Wn);
                float xv = Xp[gy * Wn + gx], gv = Gp[gy * Wn + gx];
                su[o + i] = __builtin_amdgcn_cvt_pkrtz(xv, xv * gv);
            }
        }
    }
    __syncthreads();
    hbox_h2(su, hx, t);        // packed fp16 sliding sums, both planes
    __syncthreads();

    float2 m[4];
    vbox4_h2(hx, x, r0, m);

    // epilogue operand loads (PDM is L3-resident; latency hidden by occupancy)
    const float4* Pp = PDM + (size_t)b * HW;
    int pbase = (ty0 + r0) * Wn + tx0 + x;
    h2* Ap = AB + (size_t)pc * HW;
#pragma unroll
    for (int j = 0; j < 4; ++j) {
        float4 pdm = Pp[pbase + j * Wn];
        float mx = m[j].x, mxg = m[j].y;
        float a = (mxg - pdm.z * mx + pdm.x) * pdm.y;  // *invD
        float bb = mx - a * pdm.z;
        Ap[pbase + j * Wn] = __builtin_amdgcn_cvt_pkrtz(a, bb);
    }
}

// ---------------- K6: out = box11(a)*G + box11(b) (packed fp16, pk math, 2 barriers) ----------------
__global__ void __launch_bounds__(256) k_out(
        const h2* __restrict__ AB, const float* __restrict__ G,
        float* __restrict__ out) {
    __shared__ h2 su[SSZ];     // packed (a,b) fp16 pairs, pitch 49
    __shared__ h2 hx[HSZ];
    int t = threadIdx.x;
    int pc = blockIdx.y, b = pc >> 4;
    int tile = swz_tile(blockIdx.x);
    int tx0 = (tile & 15) * TS, ty0 = (tile >> 4) * TS;
    int x = t & 31, wg = t >> 5, r0 = wg * 4;

    const h2* Ap = AB + (size_t)pc * HW;
    for (int u = t; u < HALO * 12; u += 256) {
        int ly = u / 12, k = u - ly * 12;
        int gy = refl(ty0 - 5 + ly, Hn);
        int col = tx0 - 8 + 4 * k;
        int o = ly * PW + 4 * k;
        if (col >= 0 && col <= Wn - 4) {
            uint4 v = *(const uint4*)((const unsigned int*)(Ap + gy * Wn + col));
            su[o] = u2h(v.x); su[o + 1] = u2h(v.y);
            su[o + 2] = u2h(v.z); su[o + 3] = u2h(v.w);
        } else {
#pragma unroll
            for (int i = 0; i < 4; ++i) {
                int gx = refl(col + i, Wn);
                su[o + i] = Ap[gy * Wn + gx];
            }
        }
    }
    __syncthreads();
    hbox_h2(su, hx, t);        // packed fp16 sliding sums (a, b)
    __syncthreads();

    float2 m[4];
    vbox4_h2(hx, x, r0, m);

    // epilogue G loads (G is L2-resident across 16 channels)
    const float* Gp = G + (size_t)b * HW;
    int pbase = (ty0 + r0) * Wn + tx0 + x;
    float* op = out + (size_t)pc * HW;
#pragma unroll
    for (int j = 0; j < 4; ++j)
        op[pbase + j * Wn] = m[j].x * Gp[pbase + j * Wn] + m[j].y;
}

extern "C" void kernel_launch(void* const* d_in, const int* in_sizes, int n_in,
                              void* d_out, int out_size, void* d_ws, size_t ws_size,
                              hipStream_t stream) {
    const float* X = (const float*)d_in[0];
    const float* G = (const float*)d_in[1];
    float* out = (float*)d_out;
    float* ws = (float*)d_ws;

    float* Xs   = ws + 0 * (size_t)NP;
    float* chi  = ws + 1 * (size_t)NP;
    float* taur = ws + 2 * (size_t)NP;
    float* vr   = ws + 3 * (size_t)NP;
    float* muG  = ws + 4 * (size_t)NP;
    float* chig = ws + 5 * (size_t)NP;
    float* nu   = ws + 6 * (size_t)NP;
    float4* PDM = (float4*)(ws + 7 * (size_t)NP);      // 4*NP floats
    h2* AB      = (h2*)(ws + 11 * (size_t)NP);         // NX h2 (4B each)
    float* ps1  = ws + 43 * (size_t)NP;
    float* ps2  = ps1 + 1024;
    float* ps3  = ps2 + 1024;
    float* ps4  = ps3 + 1024;
    float* sc   = ps4 + 1024;   // 16 scalars

    dim3 blk(256);
    k_xs<<<(NP / 4) / 256, blk, 0, stream>>>(X, Xs);

    dim3 gplane(NT, Bn);
    k_ssim<<<gplane, blk, 0, stream>>>(Xs, G, muG, vr, taur, chig, nu, chi,
                                       ps1, ps2, ps3, ps4);
    k_red<<<8, blk, 0, stream>>>(ps1, ps2, ps3, ps4, sc);
    k_pd<<<(NP / 4) / 256, blk, 0, stream>>>(chi, chig, nu, taur, vr, muG, sc, PDM);

    dim3 gchan(NT, Bn * Cn);
    k_ab<<<gchan, blk, 0, stream>>>(X, G, PDM, AB);
    k_out<<<gchan, blk, 0, stream>>>(AB, G, out);
}